// Round 3
// baseline (331.710 us; speedup 1.0000x reference)
//
#include <hip/hip_runtime.h>
#include <hip/hip_cooperative_groups.h>

namespace cg = cooperative_groups;

// Scatter-add inverted to gather, scan-free — now SINGLE cooperative kernel:
//   phase A: zero counts  -> grid.sync()
//   phase B: bucket fill (padded buckets, int atomics) -> grid.sync()
//   phase C: gather (one wave per output row, grid-stride; writes every row
//            exactly once, no fp atomics, no d_out memset)
// MAXD=12 padded slots per output row. 32768 sources over 65536 rows is
// Poisson(0.5): P(count>12 anywhere) ~ 1e-5. Overflow is still CORRECT via a
// rescan-of-idx fallback (slow path, effectively never taken).
//
// Revision history:
//  - r0 (40.8 us): 3 dispatches (memset, fill, gather).
//  - r1 (51.1 us, REGRESSED): + nontemporal hints. NT defeats L2
//    write-combining on the 128 MiB store stream. Reverted.
//  - r2 (41.3 us): contiguous lane layout, no NT. Confirms gather is at
//    ~roofline; residual ~10 us = dispatch serialization (tiny memset +
//    latency-bound fill + 2 drain gaps).
//  - r3 (this): fuse everything into one cooperative kernel, 2 grid syncs.
//    Also: row_ids loaded unconditionally (breaks counts->row_ids dependent
//    chain; slots >= cnt are only consulted when cnt>MAXD, in which case all
//    MAXD slots were written this run).

#define MAXD 12

typedef float f32x4 __attribute__((ext_vector_type(4)));

__global__ void __launch_bounds__(256) fused_kernel(
        const float* __restrict__ in,
        const int* __restrict__ idx,
        float* __restrict__ out,
        int* __restrict__ counts,
        int* __restrict__ row_ids,
        int C, int n_rows, int R) {
    cg::grid_group grid = cg::this_grid();

    int tid = blockIdx.x * blockDim.x + threadIdx.x;
    int T   = gridDim.x * blockDim.x;

    // ---- Phase A: zero the counts array (256 KB). ----
    for (int i = tid; i < R; i += T) counts[i] = 0;
    grid.sync();

    // ---- Phase B: bucket fill. ----
    for (int i = tid; i < n_rows; i += T) {
        int d = idx[i];
        int pos = atomicAdd(&counts[d], 1);
        if (pos < MAXD) row_ids[d * MAXD + pos] = i;
    }
    grid.sync();

    // ---- Phase C: gather. One wave per output row, grid-stride. ----
    int wave = tid >> 6;
    int lane = threadIdx.x & 63;
    int W    = T >> 6;

    long col0 = (long)lane * 4;             // bytes [0,1024) of the row
    long col1 = (long)(C >> 1) + lane * 4;  // bytes [1024,2048) of the row

    for (int row = wave; row < R; row += W) {
        int cnt = counts[row];
        // Unconditional slot load: no dependency on cnt. Slots >= cnt are
        // garbage but are only consulted (a) via shfl for j < min(cnt,MAXD),
        // or (b) in the overflow fallback, where cnt > MAXD implies all MAXD
        // slots were written this run.
        int myid = (lane < MAXD) ? row_ids[row * MAXD + lane] : -1;

        f32x4 a0 = 0.f;
        f32x4 a1 = 0.f;

        int m = (cnt < MAXD) ? cnt : MAXD;
        for (int j = 0; j < m; ++j) {
            int src = __shfl(myid, j);              // wave-uniform
            const f32x4* p0 = reinterpret_cast<const f32x4*>(in + (long)src * C + col0);
            const f32x4* p1 = reinterpret_cast<const f32x4*>(in + (long)src * C + col1);
            a0 += *p0;
            a1 += *p1;
        }

        if (cnt > MAXD) {
            // Overflow fallback (probability ~1e-5, but keeps the kernel
            // correct unconditionally): rescan idx for sources of this row
            // not captured in the padded bucket.
            for (int r = 0; r < n_rows; ++r) {
                if (__builtin_expect(idx[r] == row, 0)) {
                    bool captured = __any((lane < MAXD) && (myid == r));
                    if (!captured) {
                        const f32x4* p0 = reinterpret_cast<const f32x4*>(in + (long)r * C + col0);
                        const f32x4* p1 = reinterpret_cast<const f32x4*>(in + (long)r * C + col1);
                        a0 += *p0;
                        a1 += *p1;
                    }
                }
            }
        }

        *reinterpret_cast<f32x4*>(out + (long)row * C + col0) = a0;
        *reinterpret_cast<f32x4*>(out + (long)row * C + col1) = a1;
    }
}

extern "C" void kernel_launch(void* const* d_in, const int* in_sizes, int n_in,
                              void* d_out, int out_size, void* d_ws, size_t ws_size,
                              hipStream_t stream) {
    const float* in  = (const float*)d_in[0];
    const int*   idx = (const int*)d_in[1];
    float*       out = (float*)d_out;

    int n_rows = in_sizes[1];             // 32768 sources
    int C      = in_sizes[0] / n_rows;    // 512
    int R      = out_size / C;            // 65536 output rows (B*L)

    int* counts  = (int*)d_ws;            // R ints
    int* row_ids = counts + R;            // R*MAXD ints (~3 MiB)

    // Cooperative grid: max co-resident blocks (queried once; pure host-side
    // queries, safe under graph capture).
    static int grid = 0;
    if (grid == 0) {
        int blocks_per_cu = 0;
        hipError_t e = hipOccupancyMaxActiveBlocksPerMultiprocessor(
            &blocks_per_cu, (const void*)fused_kernel, 256, 0);
        int num_cu = 256;
        hipDeviceProp_t prop;
        int dev = 0;
        if (hipGetDevice(&dev) == hipSuccess &&
            hipGetDeviceProperties(&prop, dev) == hipSuccess) {
            num_cu = prop.multiProcessorCount;
        }
        if (e != hipSuccess || blocks_per_cu < 1) blocks_per_cu = 4;  // safe floor
        grid = blocks_per_cu * num_cu;
        int max_useful = (R * 64 + 255) / 256;  // one wave per row is plenty
        if (grid > max_useful) grid = max_useful;
    }

    void* args[] = {(void*)&in, (void*)&idx, (void*)&out,
                    (void*)&counts, (void*)&row_ids,
                    (void*)&C, (void*)&n_rows, (void*)&R};
    hipLaunchCooperativeKernel((const void*)fused_kernel, dim3(grid), dim3(256),
                               args, 0, stream);
}

// Round 4
// 329.803 us; speedup vs baseline: 1.0058x; 1.0058x over previous
//
#include <hip/hip_runtime.h>

// Scatter-add inverted to gather, scan-free — single fused dispatch:
//   phase A: zero counts -> BARRIER -> phase B: bucket fill (int atomics)
//   -> BARRIER -> phase C: gather (one wave per output row, grid-stride).
// MAXD=12 padded slots per output row. 32768 sources over 65536 rows is
// Poisson(0.5): P(count>12 anywhere) ~ 1e-5. Overflow is still CORRECT via a
// rescan-of-idx fallback (slow path, effectively never taken).
//
// Revision history:
//  - r0 (40.8 us): 3 dispatches (memset, fill, gather).
//  - r1 (51.1 us, REGRESSED): nontemporal hints defeat L2 write-combining on
//    the 128 MiB store stream. Reverted.
//  - r2 (41.3 us): contiguous lane layout; gather ~at mixed-stream roofline;
//    residual ~10 us = dispatch serialization.
//  - r3 (331.7 us, CATASTROPHIC): cg::grid.sync() costs ~150 us/sync on ROCm
//    (Occupancy 92%, VALUBusy 1.1%, 113 GB/s = all waves parked in the cg
//    software barrier). Fusion idea fine, cg implementation unusable.
//  - r4 (this): custom two-level monotonic grid barrier (64 padded leaf
//    counters -> root -> epoch, never reset, __device__ globals immune to
//    workspace re-poison; release/acquire chain for cross-XCD visibility).
//    Expected barrier cost ~2-3 us each.

#define MAXD 12
#define LEAVES 64
#define LEAF_STRIDE 32  // 128 B between leaf counters (no false sharing)

typedef float f32x4 __attribute__((ext_vector_type(4)));

// Monotonic barrier state. Zero-initialized at module load; NEVER reset.
// Invariant after the m-th barrier ever completed (grid size fixed at nb):
//   g_leaf[L] == m * leaf_n(L), g_root == m * LEAVES, g_epoch == m.
__device__ unsigned g_leaf[LEAVES * LEAF_STRIDE];
__device__ unsigned g_root;
__device__ unsigned g_epoch;

__device__ __forceinline__ void grid_barrier(unsigned e_target, int nblocks) {
    __syncthreads();
    if (threadIdx.x == 0) {
        __threadfence();  // agent-scope release of this block's prior writes
        int leaf = blockIdx.x & (LEAVES - 1);
        unsigned leaf_n = (unsigned)((nblocks - leaf + LEAVES - 1) / LEAVES);
        unsigned a = __hip_atomic_fetch_add(&g_leaf[leaf * LEAF_STRIDE], 1u,
                         __ATOMIC_ACQ_REL, __HIP_MEMORY_SCOPE_AGENT) + 1u;
        if (a == e_target * leaf_n) {
            // last block of this leaf: acquire leaf members, release into root
            unsigned r = __hip_atomic_fetch_add(&g_root, 1u,
                             __ATOMIC_ACQ_REL, __HIP_MEMORY_SCOPE_AGENT) + 1u;
            if (r == e_target * (unsigned)LEAVES) {
                // last leaf rep: acquired everyone transitively; publish epoch
                __hip_atomic_store(&g_epoch, e_target, __ATOMIC_RELEASE,
                                   __HIP_MEMORY_SCOPE_AGENT);
            }
        }
        while (__hip_atomic_load(&g_epoch, __ATOMIC_ACQUIRE,
                                 __HIP_MEMORY_SCOPE_AGENT) < e_target) {
            __builtin_amdgcn_s_sleep(2);
        }
        // acquire-load above invalidated this CU's L1; block threads below
        // are ordered by __syncthreads.
    }
    __syncthreads();
}

__global__ void __launch_bounds__(256) fused_kernel(
        const float* __restrict__ in,
        const int* __restrict__ idx,
        float* __restrict__ out,
        int* __restrict__ counts,
        int* __restrict__ row_ids,
        int C, int n_rows, int R) {
    __shared__ unsigned s_e0;
    if (threadIdx.x == 0) {
        // Safe: barrier e0+1 cannot complete until every block (including
        // this one, which reads BEFORE arriving) has arrived.
        s_e0 = __hip_atomic_load(&g_epoch, __ATOMIC_ACQUIRE,
                                 __HIP_MEMORY_SCOPE_AGENT);
    }
    __syncthreads();
    unsigned e0 = s_e0;

    int nb  = gridDim.x;
    int tid = blockIdx.x * blockDim.x + threadIdx.x;
    int T   = nb * blockDim.x;

    // ---- Phase A: zero the counts array (256 KB). ----
    for (int i = tid; i < R; i += T) counts[i] = 0;
    grid_barrier(e0 + 1, nb);

    // ---- Phase B: bucket fill. ----
    for (int i = tid; i < n_rows; i += T) {
        int d = idx[i];
        int pos = atomicAdd(&counts[d], 1);
        if (pos < MAXD) row_ids[d * MAXD + pos] = i;
    }
    grid_barrier(e0 + 2, nb);

    // ---- Phase C: gather. One wave per output row, grid-stride. ----
    int wave = tid >> 6;
    int lane = threadIdx.x & 63;
    int W    = T >> 6;

    long col0 = (long)lane * 4;             // bytes [0,1024) of the row
    long col1 = (long)(C >> 1) + lane * 4;  // bytes [1024,2048) of the row

    for (int row = wave; row < R; row += W) {
        int cnt = counts[row];
        // Unconditional slot load (no dependency on cnt): slots >= cnt are
        // garbage but only consulted via shfl for j < min(cnt,MAXD), or in
        // the overflow path where all MAXD slots were written this run.
        int myid = (lane < MAXD) ? row_ids[row * MAXD + lane] : -1;

        f32x4 a0 = 0.f;
        f32x4 a1 = 0.f;

        int m = (cnt < MAXD) ? cnt : MAXD;
        for (int j = 0; j < m; ++j) {
            int src = __shfl(myid, j);              // wave-uniform
            const f32x4* p0 = reinterpret_cast<const f32x4*>(in + (long)src * C + col0);
            const f32x4* p1 = reinterpret_cast<const f32x4*>(in + (long)src * C + col1);
            a0 += *p0;
            a1 += *p1;
        }

        if (cnt > MAXD) {
            // Overflow fallback (probability ~1e-5, correctness guarantee).
            for (int r = 0; r < n_rows; ++r) {
                if (__builtin_expect(idx[r] == row, 0)) {
                    bool captured = __any((lane < MAXD) && (myid == r));
                    if (!captured) {
                        const f32x4* p0 = reinterpret_cast<const f32x4*>(in + (long)r * C + col0);
                        const f32x4* p1 = reinterpret_cast<const f32x4*>(in + (long)r * C + col1);
                        a0 += *p0;
                        a1 += *p1;
                    }
                }
            }
        }

        *reinterpret_cast<f32x4*>(out + (long)row * C + col0) = a0;
        *reinterpret_cast<f32x4*>(out + (long)row * C + col1) = a1;
    }
}

extern "C" void kernel_launch(void* const* d_in, const int* in_sizes, int n_in,
                              void* d_out, int out_size, void* d_ws, size_t ws_size,
                              hipStream_t stream) {
    const float* in  = (const float*)d_in[0];
    const int*   idx = (const int*)d_in[1];
    float*       out = (float*)d_out;

    int n_rows = in_sizes[1];             // 32768 sources
    int C      = in_sizes[0] / n_rows;    // 512
    int R      = out_size / C;            // 65536 output rows (B*L)

    int* counts  = (int*)d_ws;            // R ints
    int* row_ids = counts + R;            // R*MAXD ints (~3 MiB)

    // Cooperative grid: max co-resident blocks (host-side queries only; safe
    // under graph capture). Grid must stay CONSTANT across launches for the
    // monotonic barrier invariant — static cache guarantees that.
    static int grid = 0;
    if (grid == 0) {
        int blocks_per_cu = 0;
        hipError_t e = hipOccupancyMaxActiveBlocksPerMultiprocessor(
            &blocks_per_cu, (const void*)fused_kernel, 256, 0);
        int num_cu = 256;
        hipDeviceProp_t prop;
        int dev = 0;
        if (hipGetDevice(&dev) == hipSuccess &&
            hipGetDeviceProperties(&prop, dev) == hipSuccess) {
            num_cu = prop.multiProcessorCount;
        }
        if (e != hipSuccess || blocks_per_cu < 1) blocks_per_cu = 4;  // floor
        grid = blocks_per_cu * num_cu;
        grid &= ~63;                       // multiple of 64 (leaf coverage)
        if (grid < 64) grid = 64;
    }

    void* args[] = {(void*)&in, (void*)&idx, (void*)&out,
                    (void*)&counts, (void*)&row_ids,
                    (void*)&C, (void*)&n_rows, (void*)&R};
    hipLaunchCooperativeKernel((const void*)fused_kernel, dim3(grid), dim3(256),
                               args, 0, stream);
}

// Round 5
// 41.216 us; speedup vs baseline: 8.0481x; 8.0018x over previous
//
#include <hip/hip_runtime.h>

// Scatter-add inverted to gather, scan-free:
//   memset(counts) -> fill (padded buckets, int atomics) -> gather (one wave
//   per output row, writes every row exactly once, no fp atomics, no d_out
//   memset).
// MAXD=12 padded slots per output row. 32768 sources over 65536 rows is
// Poisson(0.5): P(count>12 anywhere) ~ 1e-5. Overflow is still CORRECT via a
// rescan-of-idx fallback (slow path, effectively never taken).
//
// Revision history:
//  - r0 (40.8 us): 3 dispatches (memset, fill, gather).
//  - r1 (51.1 us, REGRESSED): nontemporal hints defeat L2 write-combining on
//    the 128 MiB store stream. Reverted — plain stores + L2 is the fast path
//    for write-once streams on gfx950.
//  - r2 (41.3 us): contiguous lane layout (each load/store = one 1024 B
//    wave-segment); gather at ~85-90% of mixed-stream BW ceiling.
//  - r3 (331.7 us): cg::grid.sync() fusion. ~145 us per sync.
//  - r4 (329.8 us): custom two-level monotonic barrier — IDENTICAL cost.
//    Conclusion: software grid sync on 8-XCD gfx950 is structurally ~150 us
//    (cross-XCD acquire/release = L2 invalidate/writeback storms from 2048
//    blocks), while a kernel boundary provides the same coherence in ~1-2 us
//    via the hardware end-of-kernel flush. Fusion is strictly worse than
//    3 dispatches on this platform. REVERTED to r2 structure.
//  - r5 (this): r2 + unconditional row_ids slot load (from r3): breaks the
//    counts->row_ids dependent-load chain in the gather prologue. Slots
//    >= cnt are garbage but only consulted via shfl for j < min(cnt,MAXD),
//    or in the overflow path where cnt > MAXD implies all MAXD slots were
//    written this run.

#define MAXD 12

typedef float f32x4 __attribute__((ext_vector_type(4)));

__global__ void fill_kernel(const int* __restrict__ idx, int* __restrict__ counts,
                            int* __restrict__ row_ids, int n) {
    int i = blockIdx.x * blockDim.x + threadIdx.x;
    if (i < n) {
        int d = idx[i];
        int pos = atomicAdd(&counts[d], 1);
        if (pos < MAXD) row_ids[d * MAXD + pos] = i;
    }
}

// One wave per output row; lane owns 4 floats in each half of the row (C=512).
__global__ void __launch_bounds__(256) gather_kernel(
        const float* __restrict__ in,
        const int* __restrict__ counts,
        const int* __restrict__ row_ids,
        const int* __restrict__ idx,
        float* __restrict__ out, int C, int n_rows) {
    int wave = blockIdx.x * (blockDim.x >> 6) + (threadIdx.x >> 6);
    int lane = threadIdx.x & 63;

    // Issue both metadata loads immediately; no dependence between them.
    int cnt  = counts[wave];
    int myid = (lane < MAXD) ? row_ids[wave * MAXD + lane] : -1;

    f32x4 a0 = 0.f;
    f32x4 a1 = 0.f;

    long col0 = (long)lane * 4;             // bytes [0,1024) of the row
    long col1 = (long)(C >> 1) + lane * 4;  // bytes [1024,2048) of the row

    int m = (cnt < MAXD) ? cnt : MAXD;
    for (int j = 0; j < m; ++j) {
        int src = __shfl(myid, j);              // wave-uniform
        const f32x4* p0 = reinterpret_cast<const f32x4*>(in + (long)src * C + col0);
        const f32x4* p1 = reinterpret_cast<const f32x4*>(in + (long)src * C + col1);
        a0 += *p0;
        a1 += *p1;
    }

    if (cnt > MAXD) {
        // Overflow fallback (probability ~1e-5 for this distribution, but
        // keeps the kernel correct unconditionally): rescan idx for sources
        // of this row that were not captured in the padded bucket.
        for (int r = 0; r < n_rows; ++r) {
            if (__builtin_expect(idx[r] == wave, 0)) {
                bool captured = __any((lane < MAXD) && (myid == r));
                if (!captured) {
                    const f32x4* p0 = reinterpret_cast<const f32x4*>(in + (long)r * C + col0);
                    const f32x4* p1 = reinterpret_cast<const f32x4*>(in + (long)r * C + col1);
                    a0 += *p0;
                    a1 += *p1;
                }
            }
        }
    }

    *reinterpret_cast<f32x4*>(out + (long)wave * C + col0) = a0;
    *reinterpret_cast<f32x4*>(out + (long)wave * C + col1) = a1;
}

extern "C" void kernel_launch(void* const* d_in, const int* in_sizes, int n_in,
                              void* d_out, int out_size, void* d_ws, size_t ws_size,
                              hipStream_t stream) {
    const float* in  = (const float*)d_in[0];
    const int*   idx = (const int*)d_in[1];
    float*       out = (float*)d_out;

    int n_rows = in_sizes[1];             // 32768 sources
    int C      = in_sizes[0] / n_rows;    // 512
    int R      = out_size / C;            // 65536 output rows (B*L)

    int* counts  = (int*)d_ws;            // R ints
    int* row_ids = counts + R;            // R*MAXD ints (~3 MiB)

    hipMemsetAsync(counts, 0, (size_t)R * sizeof(int), stream);

    int block = 256;
    fill_kernel<<<(n_rows + block - 1) / block, block, 0, stream>>>(idx, counts, row_ids, n_rows);

    int waves_per_block = block / 64;     // one wave per output row
    int grid = (R + waves_per_block - 1) / waves_per_block;
    gather_kernel<<<grid, block, 0, stream>>>(in, counts, row_ids, idx, out, C, n_rows);
}